// Round 1
// baseline (761.904 us; speedup 1.0000x reference)
//
#include <hip/hip_runtime.h>
#include <math.h>

#define N_NODES 50000
#define N_EDGES 800000
#define D 128
#define NPAD 50048   // N rounded up, keeps segments 16B-aligned

// ---------------------------------------------------------------------------
// CSR build: counts -> exclusive scan -> fill (so aggregation needs no atomics)
// ---------------------------------------------------------------------------

__global__ void k_zero(int* __restrict__ counts) {
    int i = blockIdx.x * blockDim.x + threadIdx.x;
    if (i < N_NODES) counts[i] = 0;
}

__global__ void k_count(const int* __restrict__ col, int* __restrict__ counts) {
    int i = blockIdx.x * blockDim.x + threadIdx.x;
    if (i < N_EDGES) atomicAdd(&counts[col[i]], 1);
}

// single-block exclusive scan over N_NODES counts -> offsets[N+1], cursor copy
__global__ __launch_bounds__(1024) void k_scan(const int* __restrict__ counts,
                                               int* __restrict__ offsets,
                                               int* __restrict__ cursor) {
    __shared__ int sums[16];
    __shared__ int base_s;
    int tid = threadIdx.x;
    int lane = tid & 63, wv = tid >> 6;
    if (tid == 0) base_s = 0;
    __syncthreads();
    for (int start = 0; start < N_NODES; start += 1024) {
        int i = start + tid;
        int v = (i < N_NODES) ? counts[i] : 0;
        int x = v;
        #pragma unroll
        for (int off = 1; off < 64; off <<= 1) {
            int y = __shfl_up(x, off);
            if (lane >= off) x += y;
        }
        if (lane == 63) sums[wv] = x;
        __syncthreads();
        if (tid < 16) {
            int s = sums[tid];
            #pragma unroll
            for (int off = 1; off < 16; off <<= 1) {
                int y = __shfl_up(s, off);
                if (tid >= off) s += y;
            }
            sums[tid] = s;
        }
        __syncthreads();
        int waveoff = (wv == 0) ? 0 : sums[wv - 1];
        int excl = base_s + waveoff + x - v;
        if (i < N_NODES) { offsets[i] = excl; cursor[i] = excl; }
        int chunk_total = sums[15];
        __syncthreads();
        if (tid == 0) base_s += chunk_total;
    }
    if (tid == 0) offsets[N_NODES] = base_s;  // == N_EDGES
}

__global__ void k_fill(const int* __restrict__ row, const int* __restrict__ col,
                       int* __restrict__ cursor, int* __restrict__ csr_rows) {
    int i = blockIdx.x * blockDim.x + threadIdx.x;
    if (i < N_EDGES) {
        int pos = atomicAdd(&cursor[col[i]], 1);
        csr_rows[pos] = row[i];
    }
}

__global__ void k_dinv(const int* __restrict__ counts, float* __restrict__ dinv) {
    int i = blockIdx.x * blockDim.x + threadIdx.x;
    if (i < N_NODES) dinv[i] = rsqrtf((float)counts[i] + 1.0f);  // +1 self-loop
}

// ---------------------------------------------------------------------------
// GEMM: hw[N,D] = h[N,D] @ W[D,D].  W staged fully in LDS (64KB), 32-row tile,
// 4x4 register tile per thread, float4 LDS reads.
// ---------------------------------------------------------------------------
#define BM 32

__global__ __launch_bounds__(256) void k_gemm(const float* __restrict__ h, int h_stride,
                                              const float* __restrict__ W,
                                              float* __restrict__ hw) {
    __shared__ float Ws[D * D];      // 64 KB
    __shared__ float hs[BM * D];     // 16 KB
    int tid = threadIdx.x;

    // stage W: 4096 float4, 16 per thread (coalesced)
    const float4* W4 = (const float4*)W;
    float4* Ws4 = (float4*)Ws;
    #pragma unroll
    for (int i = 0; i < 16; ++i) Ws4[tid + 256 * i] = W4[tid + 256 * i];

    // stage h tile: 1024 float4, 4 per thread
    int row0 = blockIdx.x * BM;
    float4* hs4 = (float4*)hs;
    #pragma unroll
    for (int i = 0; i < 4; ++i) {
        int idx = tid + 256 * i;
        int r = idx >> 5, c4 = idx & 31;
        int row = row0 + r;
        float4 v = make_float4(0.f, 0.f, 0.f, 0.f);
        if (row < N_NODES) v = *(const float4*)(h + (size_t)row * h_stride + c4 * 4);
        hs4[idx] = v;
    }
    __syncthreads();

    int tx = tid & 31;   // cols 4*tx .. 4*tx+3
    int ty = tid >> 5;   // rows 4*ty .. 4*ty+3
    float acc[4][4] = {};
    for (int k = 0; k < D; k += 4) {
        float4 a[4], bv[4];
        #pragma unroll
        for (int i = 0; i < 4; ++i) a[i] = *(float4*)(hs + (4 * ty + i) * D + k);
        #pragma unroll
        for (int j = 0; j < 4; ++j) bv[j] = *(float4*)(Ws + (k + j) * D + 4 * tx);
        #pragma unroll
        for (int i = 0; i < 4; ++i) {
            float4 aa = a[i];
            acc[i][0] += aa.x * bv[0].x; acc[i][1] += aa.x * bv[0].y;
            acc[i][2] += aa.x * bv[0].z; acc[i][3] += aa.x * bv[0].w;
            acc[i][0] += aa.y * bv[1].x; acc[i][1] += aa.y * bv[1].y;
            acc[i][2] += aa.y * bv[1].z; acc[i][3] += aa.y * bv[1].w;
            acc[i][0] += aa.z * bv[2].x; acc[i][1] += aa.z * bv[2].y;
            acc[i][2] += aa.z * bv[2].z; acc[i][3] += aa.z * bv[2].w;
            acc[i][0] += aa.w * bv[3].x; acc[i][1] += aa.w * bv[3].y;
            acc[i][2] += aa.w * bv[3].z; acc[i][3] += aa.w * bv[3].w;
        }
    }
    #pragma unroll
    for (int i = 0; i < 4; ++i) {
        int row = row0 + 4 * ty + i;
        if (row < N_NODES) {
            float4 v = make_float4(acc[i][0], acc[i][1], acc[i][2], acc[i][3]);
            *(float4*)(hw + (size_t)row * D + 4 * tx) = v;
        }
    }
}

// ---------------------------------------------------------------------------
// Aggregate: out[node,layer,:] = tanh( dinv[node]*( sum_{e:col=node} dinv[row]*hw[row]
//                                                   + dinv[node]*hw[node] ) + b )
// 2 nodes per 256-thread block; thread c owns one feature column.
// ---------------------------------------------------------------------------
__global__ __launch_bounds__(256) void k_agg(const float* __restrict__ hw,
                                             const float* __restrict__ dinv,
                                             const int* __restrict__ offsets,
                                             const int* __restrict__ csr_rows,
                                             const float* __restrict__ bias,
                                             float* __restrict__ out, int layer) {
    int node = blockIdx.x * 2 + (threadIdx.x >> 7);
    int c = threadIdx.x & 127;
    float di = dinv[node];
    float acc = di * hw[node * D + c];           // self-loop (inner dinv factor)
    int s = offsets[node], e = offsets[node + 1];
    for (int j = s; j < e; ++j) {
        int r = csr_rows[j];
        acc += dinv[r] * hw[r * D + c];
    }
    float v = tanhf(di * acc + bias[c]);
    out[(node * 3 + layer) * D + c] = v;
}

// ---------------------------------------------------------------------------

extern "C" void kernel_launch(void* const* d_in, const int* in_sizes, int n_in,
                              void* d_out, int out_size, void* d_ws, size_t ws_size,
                              hipStream_t stream) {
    const float* x  = (const float*)d_in[0];
    const int*   ei = (const int*)d_in[1];
    const float* W0 = (const float*)d_in[2];
    const float* b0 = (const float*)d_in[3];
    const float* W1 = (const float*)d_in[4];
    const float* b1 = (const float*)d_in[5];
    const float* W2 = (const float*)d_in[6];
    const float* b2 = (const float*)d_in[7];
    float* out = (float*)d_out;

    const int* row = ei;             // edge_index[0]
    const int* col = ei + N_EDGES;   // edge_index[1]

    // workspace layout
    float* dinv    = (float*)d_ws;                 // NPAD floats
    int*   counts  = (int*)(dinv + NPAD);          // NPAD
    int*   offsets = counts + NPAD;                // NPAD (N+1 used)
    int*   cursor  = offsets + NPAD;               // NPAD
    int*   csr     = cursor + NPAD;                // N_EDGES
    float* hw      = (float*)(csr + N_EDGES);      // N*D floats (25.6 MB)

    int nb_n = (N_NODES + 255) / 256;
    int nb_e = (N_EDGES + 255) / 256;

    k_zero<<<nb_n, 256, 0, stream>>>(counts);
    k_count<<<nb_e, 256, 0, stream>>>(col, counts);
    k_scan<<<1, 1024, 0, stream>>>(counts, offsets, cursor);
    k_fill<<<nb_e, 256, 0, stream>>>(row, col, cursor, csr);
    k_dinv<<<nb_n, 256, 0, stream>>>(counts, dinv);

    int nb_gemm = (N_NODES + BM - 1) / BM;
    int nb_agg  = N_NODES / 2;

    const float* Ws_[3] = {W0, W1, W2};
    const float* bs_[3] = {b0, b1, b2};
    for (int l = 0; l < 3; ++l) {
        const float* h;
        int stride;
        if (l == 0) { h = x; stride = D; }
        else        { h = out + (size_t)(l - 1) * D; stride = 3 * D; }
        k_gemm<<<nb_gemm, 256, 0, stream>>>(h, stride, Ws_[l], hw);
        k_agg<<<nb_agg, 256, 0, stream>>>(hw, dinv, offsets, csr, bs_[l], out, l);
    }
}

// Round 2
// 454.678 us; speedup vs baseline: 1.6757x; 1.6757x over previous
//
#include <hip/hip_runtime.h>
#include <math.h>

#define N_NODES 50000
#define N_EDGES 800000
#define D 128
#define NPAD 50048   // N rounded up, keeps segments 16B-aligned
#define NBLK 196     // ceil(N_NODES/256)

// ---------------------------------------------------------------------------
// CSR build: counts -> multi-block exclusive scan -> fill (no atomics in agg)
// ---------------------------------------------------------------------------

__global__ void k_zero(int* __restrict__ counts) {
    int i = blockIdx.x * blockDim.x + threadIdx.x;
    if (i < N_NODES) counts[i] = 0;
}

__global__ void k_count(const int* __restrict__ col, int* __restrict__ counts) {
    int i = blockIdx.x * blockDim.x + threadIdx.x;
    if (i < N_EDGES) atomicAdd(&counts[col[i]], 1);
}

// per-block local exclusive scan of 256 counts + block total
__global__ __launch_bounds__(256) void k_scan_local(const int* __restrict__ counts,
                                                    int* __restrict__ offsets,
                                                    int* __restrict__ partials) {
    __shared__ int wsum[4];
    int tid = threadIdx.x;
    int i = blockIdx.x * 256 + tid;
    int v = (i < N_NODES) ? counts[i] : 0;
    int lane = tid & 63, wv = tid >> 6;
    int x = v;
    #pragma unroll
    for (int off = 1; off < 64; off <<= 1) {
        int y = __shfl_up(x, off);
        if (lane >= off) x += y;
    }
    if (lane == 63) wsum[wv] = x;
    __syncthreads();
    int b0 = wsum[0], b1 = wsum[1], b2 = wsum[2], b3 = wsum[3];
    int base = (wv > 0 ? b0 : 0) + (wv > 1 ? b1 : 0) + (wv > 2 ? b2 : 0);
    if (i < N_NODES) offsets[i] = base + x - v;
    if (tid == 255) partials[blockIdx.x] = b0 + b1 + b2 + b3;
}

// single small block: exclusive scan of the 196 block totals
__global__ __launch_bounds__(256) void k_scan_part(int* __restrict__ partials) {
    __shared__ int wsum[4];
    int tid = threadIdx.x;
    int v = (tid < NBLK) ? partials[tid] : 0;
    int lane = tid & 63, wv = tid >> 6;
    int x = v;
    #pragma unroll
    for (int off = 1; off < 64; off <<= 1) {
        int y = __shfl_up(x, off);
        if (lane >= off) x += y;
    }
    if (lane == 63) wsum[wv] = x;
    __syncthreads();
    int base = (wv > 0 ? wsum[0] : 0) + (wv > 1 ? wsum[1] : 0) + (wv > 2 ? wsum[2] : 0);
    if (tid < NBLK) partials[tid] = base + x - v;
}

// add scanned base, copy to cursor, compute dinv
__global__ __launch_bounds__(256) void k_scan_add(int* __restrict__ offsets,
                                                  int* __restrict__ cursor,
                                                  const int* __restrict__ partials,
                                                  const int* __restrict__ counts,
                                                  float* __restrict__ dinv) {
    int i = blockIdx.x * 256 + threadIdx.x;
    if (i < N_NODES) {
        int o = offsets[i] + partials[blockIdx.x];
        offsets[i] = o;
        cursor[i] = o;
        dinv[i] = rsqrtf((float)counts[i] + 1.0f);  // +1 self-loop
    }
    if (i == 0) offsets[N_NODES] = N_EDGES;
}

__global__ void k_fill(const int* __restrict__ row, const int* __restrict__ col,
                       int* __restrict__ cursor, int* __restrict__ csr_rows) {
    int i = blockIdx.x * blockDim.x + threadIdx.x;
    if (i < N_EDGES) {
        int pos = atomicAdd(&cursor[col[i]], 1);
        csr_rows[pos] = row[i];
    }
}

// ---------------------------------------------------------------------------
// GEMM: hw_s[N,D] = dinv[.] * (h[N,D] @ W[D,D]).  W fully in LDS, 32-row tile,
// 4x4 register tile per thread, dinv folded into epilogue.
// ---------------------------------------------------------------------------
#define BM 32

__global__ __launch_bounds__(256) void k_gemm(const float* __restrict__ h, int h_stride,
                                              const float* __restrict__ W,
                                              const float* __restrict__ dinv,
                                              float* __restrict__ hw) {
    __shared__ float Ws[D * D];      // 64 KB
    __shared__ float hs[BM * D];     // 16 KB
    int tid = threadIdx.x;

    const float4* W4 = (const float4*)W;
    float4* Ws4 = (float4*)Ws;
    #pragma unroll
    for (int i = 0; i < 16; ++i) Ws4[tid + 256 * i] = W4[tid + 256 * i];

    int row0 = blockIdx.x * BM;
    float4* hs4 = (float4*)hs;
    #pragma unroll
    for (int i = 0; i < 4; ++i) {
        int idx = tid + 256 * i;
        int r = idx >> 5, c4 = idx & 31;
        int row = row0 + r;
        float4 v = make_float4(0.f, 0.f, 0.f, 0.f);
        if (row < N_NODES) v = *(const float4*)(h + (size_t)row * h_stride + c4 * 4);
        hs4[idx] = v;
    }
    __syncthreads();

    int tx = tid & 31;
    int ty = tid >> 5;
    float acc[4][4] = {};
    for (int k = 0; k < D; k += 4) {
        float4 a[4], bv[4];
        #pragma unroll
        for (int i = 0; i < 4; ++i) a[i] = *(float4*)(hs + (4 * ty + i) * D + k);
        #pragma unroll
        for (int j = 0; j < 4; ++j) bv[j] = *(float4*)(Ws + (k + j) * D + 4 * tx);
        #pragma unroll
        for (int i = 0; i < 4; ++i) {
            float4 aa = a[i];
            acc[i][0] += aa.x * bv[0].x; acc[i][1] += aa.x * bv[0].y;
            acc[i][2] += aa.x * bv[0].z; acc[i][3] += aa.x * bv[0].w;
            acc[i][0] += aa.y * bv[1].x; acc[i][1] += aa.y * bv[1].y;
            acc[i][2] += aa.y * bv[1].z; acc[i][3] += aa.y * bv[1].w;
            acc[i][0] += aa.z * bv[2].x; acc[i][1] += aa.z * bv[2].y;
            acc[i][2] += aa.z * bv[2].z; acc[i][3] += aa.z * bv[2].w;
            acc[i][0] += aa.w * bv[3].x; acc[i][1] += aa.w * bv[3].y;
            acc[i][2] += aa.w * bv[3].z; acc[i][3] += aa.w * bv[3].w;
        }
    }
    #pragma unroll
    for (int i = 0; i < 4; ++i) {
        int row = row0 + 4 * ty + i;
        if (row < N_NODES) {
            float dr = dinv[row];
            float4 v = make_float4(acc[i][0] * dr, acc[i][1] * dr,
                                   acc[i][2] * dr, acc[i][3] * dr);
            *(float4*)(hw + (size_t)row * D + 4 * tx) = v;
        }
    }
}

// ---------------------------------------------------------------------------
// Aggregate: one WAVE per node. Lane l: half h=l>>5 handles edges j%2==h,
// ls=l&31 handles cols 4*ls..4*ls+3 (float4). 2 edges/iter, unroll x2.
// out[node,layer,:] = tanh( dinv[node]*(sum hw_s[row] + hw_s[node]) + b )
// ---------------------------------------------------------------------------
__global__ __launch_bounds__(256) void k_agg(const float* __restrict__ hw,
                                             const float* __restrict__ dinv,
                                             const int* __restrict__ offsets,
                                             const int* __restrict__ csr_rows,
                                             const float* __restrict__ bias,
                                             float* __restrict__ out, int layer) {
    int node = blockIdx.x * 4 + (threadIdx.x >> 6);
    int lane = threadIdx.x & 63;
    int h = lane >> 5;
    int ls = lane & 31;

    float4 acc = make_float4(0.f, 0.f, 0.f, 0.f);
    int s = offsets[node], e = offsets[node + 1];
    int j = s + h;
    for (; j + 2 < e; j += 4) {
        int r0 = csr_rows[j];
        int r1 = csr_rows[j + 2];
        float4 v0 = *((const float4*)(hw + (size_t)r0 * D) + ls);
        float4 v1 = *((const float4*)(hw + (size_t)r1 * D) + ls);
        acc.x += v0.x + v1.x; acc.y += v0.y + v1.y;
        acc.z += v0.z + v1.z; acc.w += v0.w + v1.w;
    }
    if (j < e) {
        int r = csr_rows[j];
        float4 v = *((const float4*)(hw + (size_t)r * D) + ls);
        acc.x += v.x; acc.y += v.y; acc.z += v.z; acc.w += v.w;
    }
    // cross-half reduce (edge parity halves hold same columns)
    acc.x += __shfl_xor(acc.x, 32);
    acc.y += __shfl_xor(acc.y, 32);
    acc.z += __shfl_xor(acc.z, 32);
    acc.w += __shfl_xor(acc.w, 32);

    if (h == 0) {
        float di = dinv[node];
        float4 self = *((const float4*)(hw + (size_t)node * D) + ls);
        float4 b = *((const float4*)bias + ls);
        float4 o;
        o.x = tanhf(di * (acc.x + self.x) + b.x);
        o.y = tanhf(di * (acc.y + self.y) + b.y);
        o.z = tanhf(di * (acc.z + self.z) + b.z);
        o.w = tanhf(di * (acc.w + self.w) + b.w);
        *((float4*)(out + ((size_t)node * 3 + layer) * D) + ls) = o;
    }
}

// ---------------------------------------------------------------------------

extern "C" void kernel_launch(void* const* d_in, const int* in_sizes, int n_in,
                              void* d_out, int out_size, void* d_ws, size_t ws_size,
                              hipStream_t stream) {
    const float* x  = (const float*)d_in[0];
    const int*   ei = (const int*)d_in[1];
    const float* W0 = (const float*)d_in[2];
    const float* b0 = (const float*)d_in[3];
    const float* W1 = (const float*)d_in[4];
    const float* b1 = (const float*)d_in[5];
    const float* W2 = (const float*)d_in[6];
    const float* b2 = (const float*)d_in[7];
    float* out = (float*)d_out;

    const int* row = ei;             // edge_index[0]
    const int* col = ei + N_EDGES;   // edge_index[1]

    // workspace layout
    float* dinv    = (float*)d_ws;                 // NPAD
    int*   counts  = (int*)(dinv + NPAD);          // NPAD
    int*   offsets = counts + NPAD;                // NPAD (N+1 used)
    int*   cursor  = offsets + NPAD;               // NPAD
    int*   partials= cursor + NPAD;                // 256
    int*   csr     = partials + 256;               // N_EDGES
    float* hw      = (float*)(csr + N_EDGES);      // N*D floats (16B-aligned)

    int nb_e = (N_EDGES + 255) / 256;

    k_zero<<<NBLK, 256, 0, stream>>>(counts);
    k_count<<<nb_e, 256, 0, stream>>>(col, counts);
    k_scan_local<<<NBLK, 256, 0, stream>>>(counts, offsets, partials);
    k_scan_part<<<1, 256, 0, stream>>>(partials);
    k_scan_add<<<NBLK, 256, 0, stream>>>(offsets, cursor, partials, counts, dinv);
    k_fill<<<nb_e, 256, 0, stream>>>(row, col, cursor, csr);

    int nb_gemm = (N_NODES + BM - 1) / BM;
    int nb_agg  = N_NODES / 4;   // 4 nodes (waves) per block

    const float* Ws_[3] = {W0, W1, W2};
    const float* bs_[3] = {b0, b1, b2};
    for (int l = 0; l < 3; ++l) {
        const float* h;
        int stride;
        if (l == 0) { h = x; stride = D; }
        else        { h = out + (size_t)(l - 1) * D; stride = 3 * D; }
        k_gemm<<<nb_gemm, 256, 0, stream>>>(h, stride, Ws_[l], dinv, hw);
        k_agg<<<nb_agg, 256, 0, stream>>>(hw, dinv, offsets, csr, bs_[l], out, l);
    }
}

// Round 3
// 393.782 us; speedup vs baseline: 1.9348x; 1.1546x over previous
//
#include <hip/hip_runtime.h>
#include <math.h>

#define N_NODES 50000
#define N_EDGES 800000
#define D 128
#define NPAD 50048   // N rounded up, keeps segments 16B-aligned
#define NBLK 196     // ceil(N_NODES/256)

typedef unsigned int uint32;
typedef unsigned short ushort16;

__device__ __forceinline__ ushort f2bf(float f) {
    uint32 u = __float_as_uint(f);
    u = (u + 0x7fff + ((u >> 16) & 1)) >> 16;   // round-to-nearest-even
    return (ushort)u;
}
__device__ __forceinline__ float bf2f(ushort u) {
    return __uint_as_float(((uint32)u) << 16);
}

// ---------------------------------------------------------------------------
// CSR build: counts -> local scan -> (fused base-reduce + add) -> fill
// ---------------------------------------------------------------------------

__global__ void k_count(const int* __restrict__ col, int* __restrict__ counts) {
    int i = blockIdx.x * blockDim.x + threadIdx.x;
    if (i < N_EDGES) atomicAdd(&counts[col[i]], 1);
}

// per-block local exclusive scan of 256 counts + block total
__global__ __launch_bounds__(256) void k_scan_local(const int* __restrict__ counts,
                                                    int* __restrict__ offsets,
                                                    int* __restrict__ partials) {
    __shared__ int wsum[4];
    int tid = threadIdx.x;
    int i = blockIdx.x * 256 + tid;
    int v = (i < N_NODES) ? counts[i] : 0;
    int lane = tid & 63, wv = tid >> 6;
    int x = v;
    #pragma unroll
    for (int off = 1; off < 64; off <<= 1) {
        int y = __shfl_up(x, off);
        if (lane >= off) x += y;
    }
    if (lane == 63) wsum[wv] = x;
    __syncthreads();
    int b0 = wsum[0], b1 = wsum[1], b2 = wsum[2], b3 = wsum[3];
    int base = (wv > 0 ? b0 : 0) + (wv > 1 ? b1 : 0) + (wv > 2 ? b2 : 0);
    if (i < N_NODES) offsets[i] = base + x - v;
    if (tid == 255) partials[blockIdx.x] = b0 + b1 + b2 + b3;
}

// fused: each block reduces partials[0..bid) redundantly, adds base,
// copies to cursor, computes dinv
__global__ __launch_bounds__(256) void k_scan_add(int* __restrict__ offsets,
                                                  int* __restrict__ cursor,
                                                  const int* __restrict__ partials,
                                                  const int* __restrict__ counts,
                                                  float* __restrict__ dinv) {
    __shared__ int wsum[4];
    int tid = threadIdx.x;
    int p = (tid < (int)blockIdx.x && tid < NBLK) ? partials[tid] : 0;
    int lane = tid & 63, wv = tid >> 6;
    #pragma unroll
    for (int off = 32; off; off >>= 1) p += __shfl_down(p, off);
    if (lane == 0) wsum[wv] = p;
    __syncthreads();
    int base = wsum[0] + wsum[1] + wsum[2] + wsum[3];
    int i = blockIdx.x * 256 + tid;
    if (i < N_NODES) {
        int o = offsets[i] + base;
        offsets[i] = o;
        cursor[i] = o;
        dinv[i] = rsqrtf((float)counts[i] + 1.0f);  // +1 self-loop
    }
    if (i == 0) offsets[N_NODES] = N_EDGES;
}

__global__ void k_fill(const int* __restrict__ row, const int* __restrict__ col,
                       int* __restrict__ cursor, int* __restrict__ csr_rows) {
    int i = blockIdx.x * blockDim.x + threadIdx.x;
    if (i < N_EDGES) {
        int pos = atomicAdd(&cursor[col[i]], 1);
        csr_rows[pos] = row[i];
    }
}

// ---------------------------------------------------------------------------
// GEMM: hw_bf16[N,D] = bf16( dinv[.] * (h[N,D] @ W[D,D]) ).  W in LDS,
// 32-row tile, 4x4 register tile, dinv + bf16-convert in epilogue.
// ---------------------------------------------------------------------------
#define BM 32

__global__ __launch_bounds__(256) void k_gemm(const float* __restrict__ h, int h_stride,
                                              const float* __restrict__ W,
                                              const float* __restrict__ dinv,
                                              ushort* __restrict__ hw) {
    __shared__ float Ws[D * D];      // 64 KB
    __shared__ float hs[BM * D];     // 16 KB
    int tid = threadIdx.x;

    const float4* W4 = (const float4*)W;
    float4* Ws4 = (float4*)Ws;
    #pragma unroll
    for (int i = 0; i < 16; ++i) Ws4[tid + 256 * i] = W4[tid + 256 * i];

    int row0 = blockIdx.x * BM;
    float4* hs4 = (float4*)hs;
    #pragma unroll
    for (int i = 0; i < 4; ++i) {
        int idx = tid + 256 * i;
        int r = idx >> 5, c4 = idx & 31;
        int row = row0 + r;
        float4 v = make_float4(0.f, 0.f, 0.f, 0.f);
        if (row < N_NODES) v = *(const float4*)(h + (size_t)row * h_stride + c4 * 4);
        hs4[idx] = v;
    }
    __syncthreads();

    int tx = tid & 31;
    int ty = tid >> 5;
    float acc[4][4] = {};
    for (int k = 0; k < D; k += 4) {
        float4 a[4], bv[4];
        #pragma unroll
        for (int i = 0; i < 4; ++i) a[i] = *(float4*)(hs + (4 * ty + i) * D + k);
        #pragma unroll
        for (int j = 0; j < 4; ++j) bv[j] = *(float4*)(Ws + (k + j) * D + 4 * tx);
        #pragma unroll
        for (int i = 0; i < 4; ++i) {
            float4 aa = a[i];
            acc[i][0] += aa.x * bv[0].x; acc[i][1] += aa.x * bv[0].y;
            acc[i][2] += aa.x * bv[0].z; acc[i][3] += aa.x * bv[0].w;
            acc[i][0] += aa.y * bv[1].x; acc[i][1] += aa.y * bv[1].y;
            acc[i][2] += aa.y * bv[1].z; acc[i][3] += aa.y * bv[1].w;
            acc[i][0] += aa.z * bv[2].x; acc[i][1] += aa.z * bv[2].y;
            acc[i][2] += aa.z * bv[2].z; acc[i][3] += aa.z * bv[2].w;
            acc[i][0] += aa.w * bv[3].x; acc[i][1] += aa.w * bv[3].y;
            acc[i][2] += aa.w * bv[3].z; acc[i][3] += aa.w * bv[3].w;
        }
    }
    #pragma unroll
    for (int i = 0; i < 4; ++i) {
        int row = row0 + 4 * ty + i;
        if (row < N_NODES) {
            float dr = dinv[row];
            ushort4 v;
            v.x = f2bf(acc[i][0] * dr);
            v.y = f2bf(acc[i][1] * dr);
            v.z = f2bf(acc[i][2] * dr);
            v.w = f2bf(acc[i][3] * dr);
            *((ushort4*)(hw + (size_t)row * D) + tx) = v;
        }
    }
}

// ---------------------------------------------------------------------------
// Aggregate (bf16 rows): one WAVE per node. Half h=lane>>5 takes edges of
// parity h; ls=lane&31 owns cols 4ls..4ls+3 via ushort4 (8B) loads.
// Main loop keeps 4 edge-rows in flight per half.
// ---------------------------------------------------------------------------
__global__ __launch_bounds__(256) void k_agg(const ushort* __restrict__ hw,
                                             const float* __restrict__ dinv,
                                             const int* __restrict__ offsets,
                                             const int* __restrict__ csr_rows,
                                             const float* __restrict__ bias,
                                             float* __restrict__ out, int layer) {
    int node = blockIdx.x * 4 + (threadIdx.x >> 6);
    int lane = threadIdx.x & 63;
    int h = lane >> 5;
    int ls = lane & 31;

    float4 acc = make_float4(0.f, 0.f, 0.f, 0.f);
    int s = offsets[node], e = offsets[node + 1];
    int j = s + h;
    for (; j + 6 < e; j += 8) {
        int r0 = csr_rows[j];
        int r1 = csr_rows[j + 2];
        int r2 = csr_rows[j + 4];
        int r3 = csr_rows[j + 6];
        ushort4 v0 = *((const ushort4*)(hw + (size_t)r0 * D) + ls);
        ushort4 v1 = *((const ushort4*)(hw + (size_t)r1 * D) + ls);
        ushort4 v2 = *((const ushort4*)(hw + (size_t)r2 * D) + ls);
        ushort4 v3 = *((const ushort4*)(hw + (size_t)r3 * D) + ls);
        acc.x += bf2f(v0.x) + bf2f(v1.x) + bf2f(v2.x) + bf2f(v3.x);
        acc.y += bf2f(v0.y) + bf2f(v1.y) + bf2f(v2.y) + bf2f(v3.y);
        acc.z += bf2f(v0.z) + bf2f(v1.z) + bf2f(v2.z) + bf2f(v3.z);
        acc.w += bf2f(v0.w) + bf2f(v1.w) + bf2f(v2.w) + bf2f(v3.w);
    }
    for (; j < e; j += 2) {
        int r = csr_rows[j];
        ushort4 v = *((const ushort4*)(hw + (size_t)r * D) + ls);
        acc.x += bf2f(v.x); acc.y += bf2f(v.y);
        acc.z += bf2f(v.z); acc.w += bf2f(v.w);
    }
    // cross-half reduce (parity halves hold the same columns)
    acc.x += __shfl_xor(acc.x, 32);
    acc.y += __shfl_xor(acc.y, 32);
    acc.z += __shfl_xor(acc.z, 32);
    acc.w += __shfl_xor(acc.w, 32);

    if (h == 0) {
        float di = dinv[node];
        ushort4 sv = *((const ushort4*)(hw + (size_t)node * D) + ls);
        float4 b = *((const float4*)bias + ls);
        float4 o;
        o.x = tanhf(di * (acc.x + bf2f(sv.x)) + b.x);
        o.y = tanhf(di * (acc.y + bf2f(sv.y)) + b.y);
        o.z = tanhf(di * (acc.z + bf2f(sv.z)) + b.z);
        o.w = tanhf(di * (acc.w + bf2f(sv.w)) + b.w);
        *((float4*)(out + ((size_t)node * 3 + layer) * D) + ls) = o;
    }
}

// ---------------------------------------------------------------------------

extern "C" void kernel_launch(void* const* d_in, const int* in_sizes, int n_in,
                              void* d_out, int out_size, void* d_ws, size_t ws_size,
                              hipStream_t stream) {
    const float* x  = (const float*)d_in[0];
    const int*   ei = (const int*)d_in[1];
    const float* W0 = (const float*)d_in[2];
    const float* b0 = (const float*)d_in[3];
    const float* W1 = (const float*)d_in[4];
    const float* b1 = (const float*)d_in[5];
    const float* W2 = (const float*)d_in[6];
    const float* b2 = (const float*)d_in[7];
    float* out = (float*)d_out;

    const int* row = ei;             // edge_index[0]
    const int* col = ei + N_EDGES;   // edge_index[1]

    // workspace layout (all segments 16B-aligned)
    float* dinv    = (float*)d_ws;                 // NPAD
    int*   counts  = (int*)(dinv + NPAD);          // NPAD
    int*   offsets = counts + NPAD;                // NPAD (N+1 used)
    int*   cursor  = offsets + NPAD;               // NPAD
    int*   partials= cursor + NPAD;                // 256
    int*   csr     = partials + 256;               // N_EDGES
    ushort* hw     = (ushort*)(csr + N_EDGES);     // N*D bf16 (12.8 MB)

    int nb_e = (N_EDGES + 255) / 256;

    hipMemsetAsync(counts, 0, NPAD * sizeof(int), stream);
    k_count<<<nb_e, 256, 0, stream>>>(col, counts);
    k_scan_local<<<NBLK, 256, 0, stream>>>(counts, offsets, partials);
    k_scan_add<<<NBLK, 256, 0, stream>>>(offsets, cursor, partials, counts, dinv);
    k_fill<<<nb_e, 256, 0, stream>>>(row, col, cursor, csr);

    int nb_gemm = (N_NODES + BM - 1) / BM;
    int nb_agg  = N_NODES / 4;   // 4 nodes (waves) per block

    const float* Ws_[3] = {W0, W1, W2};
    const float* bs_[3] = {b0, b1, b2};
    for (int l = 0; l < 3; ++l) {
        const float* h;
        int stride;
        if (l == 0) { h = x; stride = D; }
        else        { h = out + (size_t)(l - 1) * D; stride = 3 * D; }
        k_gemm<<<nb_gemm, 256, 0, stream>>>(h, stride, Ws_[l], dinv, hw);
        k_agg<<<nb_agg, 256, 0, stream>>>(hw, dinv, offsets, csr, bs_[l], out, l);
    }
}

// Round 4
// 355.654 us; speedup vs baseline: 2.1423x; 1.1072x over previous
//
#include <hip/hip_runtime.h>
#include <math.h>

#define N_NODES 50000
#define N_EDGES 800000
#define D 128
#define NPAD 50048   // N rounded up, keeps segments 16B-aligned
#define NBLK 196     // ceil(N_NODES/256)

typedef unsigned int uint32;

__device__ __forceinline__ ushort f2bf(float f) {
    uint32 u = __float_as_uint(f);
    u = (u + 0x7fff + ((u >> 16) & 1)) >> 16;   // round-to-nearest-even
    return (ushort)u;
}
__device__ __forceinline__ float bf2f(ushort u) {
    return __uint_as_float(((uint32)u) << 16);
}

// ---------------------------------------------------------------------------
// CSR build: count (+record rank) -> local scan -> fused base add -> fill
// ---------------------------------------------------------------------------

// 4 edges/thread, int4 loads; rank_buf[i] = this edge's arrival index at its
// target node. 4 independent atomic chains per thread for MLP.
__global__ __launch_bounds__(256) void k_count(const int* __restrict__ col,
                                               int* __restrict__ counts,
                                               int* __restrict__ rank_buf) {
    int i4 = (blockIdx.x * 256 + threadIdx.x) * 4;
    if (i4 < N_EDGES) {   // N_EDGES % 4 == 0 -> all-or-nothing per thread
        int4 c = *(const int4*)(col + i4);
        int4 r;
        r.x = atomicAdd(&counts[c.x], 1);
        r.y = atomicAdd(&counts[c.y], 1);
        r.z = atomicAdd(&counts[c.z], 1);
        r.w = atomicAdd(&counts[c.w], 1);
        *(int4*)(rank_buf + i4) = r;
    }
}

// per-block local exclusive scan of 256 counts + block total
__global__ __launch_bounds__(256) void k_scan_local(const int* __restrict__ counts,
                                                    int* __restrict__ offsets,
                                                    int* __restrict__ partials) {
    __shared__ int wsum[4];
    int tid = threadIdx.x;
    int i = blockIdx.x * 256 + tid;
    int v = (i < N_NODES) ? counts[i] : 0;
    int lane = tid & 63, wv = tid >> 6;
    int x = v;
    #pragma unroll
    for (int off = 1; off < 64; off <<= 1) {
        int y = __shfl_up(x, off);
        if (lane >= off) x += y;
    }
    if (lane == 63) wsum[wv] = x;
    __syncthreads();
    int b0 = wsum[0], b1 = wsum[1], b2 = wsum[2], b3 = wsum[3];
    int base = (wv > 0 ? b0 : 0) + (wv > 1 ? b1 : 0) + (wv > 2 ? b2 : 0);
    if (i < N_NODES) offsets[i] = base + x - v;
    if (tid == 255) partials[blockIdx.x] = b0 + b1 + b2 + b3;
}

// fused: each block reduces partials[0..bid) redundantly, adds base, dinv
__global__ __launch_bounds__(256) void k_scan_add(int* __restrict__ offsets,
                                                  const int* __restrict__ partials,
                                                  const int* __restrict__ counts,
                                                  float* __restrict__ dinv) {
    __shared__ int wsum[4];
    int tid = threadIdx.x;
    int p = (tid < (int)blockIdx.x && tid < NBLK) ? partials[tid] : 0;
    int lane = tid & 63, wv = tid >> 6;
    #pragma unroll
    for (int off = 32; off; off >>= 1) p += __shfl_down(p, off);
    if (lane == 0) wsum[wv] = p;
    __syncthreads();
    int base = wsum[0] + wsum[1] + wsum[2] + wsum[3];
    int i = blockIdx.x * 256 + tid;
    if (i < N_NODES) {
        offsets[i] += base;
        dinv[i] = rsqrtf((float)counts[i] + 1.0f);  // +1 self-loop
    }
    if (i == 0) offsets[N_NODES] = N_EDGES;
}

// no atomics: pos = offsets[col] + rank. 4 edges/thread, int4 loads.
__global__ __launch_bounds__(256) void k_fill(const int* __restrict__ row,
                                              const int* __restrict__ col,
                                              const int* __restrict__ offsets,
                                              const int* __restrict__ rank_buf,
                                              int* __restrict__ csr_rows) {
    int i4 = (blockIdx.x * 256 + threadIdx.x) * 4;
    if (i4 < N_EDGES) {
        int4 c = *(const int4*)(col + i4);
        int4 r = *(const int4*)(rank_buf + i4);
        int4 rw = *(const int4*)(row + i4);
        csr_rows[offsets[c.x] + r.x] = rw.x;
        csr_rows[offsets[c.y] + r.y] = rw.y;
        csr_rows[offsets[c.z] + r.z] = rw.z;
        csr_rows[offsets[c.w] + r.w] = rw.w;
    }
}

// ---------------------------------------------------------------------------
// GEMM: hw_bf16[N,D] = bf16( dinv[.] * (h[N,D] @ W[D,D]) ).  Grid-stride over
// 32-row tiles; W staged into LDS ONCE per block, amortized over ~3 tiles.
// ---------------------------------------------------------------------------
#define BM 32
#define NTILES ((N_NODES + BM - 1) / BM)   // 1563
#define GEMM_BLOCKS 512

__global__ __launch_bounds__(256) void k_gemm(const float* __restrict__ h, int h_stride,
                                              const float* __restrict__ W,
                                              const float* __restrict__ dinv,
                                              ushort* __restrict__ hw) {
    __shared__ float Ws[D * D];      // 64 KB
    __shared__ float hs[BM * D];     // 16 KB
    int tid = threadIdx.x;

    const float4* W4 = (const float4*)W;
    float4* Ws4 = (float4*)Ws;
    #pragma unroll
    for (int i = 0; i < 16; ++i) Ws4[tid + 256 * i] = W4[tid + 256 * i];

    int tx = tid & 31;
    int ty = tid >> 5;
    float4* hs4 = (float4*)hs;

    for (int t = blockIdx.x; t < NTILES; t += GEMM_BLOCKS) {
        int row0 = t * BM;
        __syncthreads();   // protect hs from previous tile's readers (also covers W once)
        #pragma unroll
        for (int i = 0; i < 4; ++i) {
            int idx = tid + 256 * i;
            int r = idx >> 5, c4 = idx & 31;
            int row = row0 + r;
            float4 v = make_float4(0.f, 0.f, 0.f, 0.f);
            if (row < N_NODES) v = *(const float4*)(h + (size_t)row * h_stride + c4 * 4);
            hs4[idx] = v;
        }
        __syncthreads();

        float acc[4][4] = {};
        for (int k = 0; k < D; k += 4) {
            float4 a[4], bv[4];
            #pragma unroll
            for (int i = 0; i < 4; ++i) a[i] = *(float4*)(hs + (4 * ty + i) * D + k);
            #pragma unroll
            for (int j = 0; j < 4; ++j) bv[j] = *(float4*)(Ws + (k + j) * D + 4 * tx);
            #pragma unroll
            for (int i = 0; i < 4; ++i) {
                float4 aa = a[i];
                acc[i][0] += aa.x * bv[0].x; acc[i][1] += aa.x * bv[0].y;
                acc[i][2] += aa.x * bv[0].z; acc[i][3] += aa.x * bv[0].w;
                acc[i][0] += aa.y * bv[1].x; acc[i][1] += aa.y * bv[1].y;
                acc[i][2] += aa.y * bv[1].z; acc[i][3] += aa.y * bv[1].w;
                acc[i][0] += aa.z * bv[2].x; acc[i][1] += aa.z * bv[2].y;
                acc[i][2] += aa.z * bv[2].z; acc[i][3] += aa.z * bv[2].w;
                acc[i][0] += aa.w * bv[3].x; acc[i][1] += aa.w * bv[3].y;
                acc[i][2] += aa.w * bv[3].z; acc[i][3] += aa.w * bv[3].w;
            }
        }
        #pragma unroll
        for (int i = 0; i < 4; ++i) {
            int row = row0 + 4 * ty + i;
            if (row < N_NODES) {
                float dr = dinv[row];
                ushort4 v;
                v.x = f2bf(acc[i][0] * dr);
                v.y = f2bf(acc[i][1] * dr);
                v.z = f2bf(acc[i][2] * dr);
                v.w = f2bf(acc[i][3] * dr);
                *((ushort4*)(hw + (size_t)row * D) + tx) = v;
            }
        }
    }
}

// ---------------------------------------------------------------------------
// Aggregate (bf16 rows): one WAVE per node. Half h=lane>>5 takes edges of
// parity h; ls=lane&31 owns cols 4ls..4ls+3 via ushort4 (8B) loads.
// ---------------------------------------------------------------------------
__global__ __launch_bounds__(256) void k_agg(const ushort* __restrict__ hw,
                                             const float* __restrict__ dinv,
                                             const int* __restrict__ offsets,
                                             const int* __restrict__ csr_rows,
                                             const float* __restrict__ bias,
                                             float* __restrict__ out, int layer) {
    int node = blockIdx.x * 4 + (threadIdx.x >> 6);
    int lane = threadIdx.x & 63;
    int h = lane >> 5;
    int ls = lane & 31;

    float4 acc = make_float4(0.f, 0.f, 0.f, 0.f);
    int s = offsets[node], e = offsets[node + 1];
    int j = s + h;
    for (; j + 6 < e; j += 8) {
        int r0 = csr_rows[j];
        int r1 = csr_rows[j + 2];
        int r2 = csr_rows[j + 4];
        int r3 = csr_rows[j + 6];
        ushort4 v0 = *((const ushort4*)(hw + (size_t)r0 * D) + ls);
        ushort4 v1 = *((const ushort4*)(hw + (size_t)r1 * D) + ls);
        ushort4 v2 = *((const ushort4*)(hw + (size_t)r2 * D) + ls);
        ushort4 v3 = *((const ushort4*)(hw + (size_t)r3 * D) + ls);
        acc.x += bf2f(v0.x) + bf2f(v1.x) + bf2f(v2.x) + bf2f(v3.x);
        acc.y += bf2f(v0.y) + bf2f(v1.y) + bf2f(v2.y) + bf2f(v3.y);
        acc.z += bf2f(v0.z) + bf2f(v1.z) + bf2f(v2.z) + bf2f(v3.z);
        acc.w += bf2f(v0.w) + bf2f(v1.w) + bf2f(v2.w) + bf2f(v3.w);
    }
    for (; j < e; j += 2) {
        int r = csr_rows[j];
        ushort4 v = *((const ushort4*)(hw + (size_t)r * D) + ls);
        acc.x += bf2f(v.x); acc.y += bf2f(v.y);
        acc.z += bf2f(v.z); acc.w += bf2f(v.w);
    }
    acc.x += __shfl_xor(acc.x, 32);
    acc.y += __shfl_xor(acc.y, 32);
    acc.z += __shfl_xor(acc.z, 32);
    acc.w += __shfl_xor(acc.w, 32);

    if (h == 0) {
        float di = dinv[node];
        ushort4 sv = *((const ushort4*)(hw + (size_t)node * D) + ls);
        float4 b = *((const float4*)bias + ls);
        float4 o;
        o.x = tanhf(di * (acc.x + bf2f(sv.x)) + b.x);
        o.y = tanhf(di * (acc.y + bf2f(sv.y)) + b.y);
        o.z = tanhf(di * (acc.z + bf2f(sv.z)) + b.z);
        o.w = tanhf(di * (acc.w + bf2f(sv.w)) + b.w);
        *((float4*)(out + ((size_t)node * 3 + layer) * D) + ls) = o;
    }
}

// ---------------------------------------------------------------------------

extern "C" void kernel_launch(void* const* d_in, const int* in_sizes, int n_in,
                              void* d_out, int out_size, void* d_ws, size_t ws_size,
                              hipStream_t stream) {
    const float* x  = (const float*)d_in[0];
    const int*   ei = (const int*)d_in[1];
    const float* W0 = (const float*)d_in[2];
    const float* b0 = (const float*)d_in[3];
    const float* W1 = (const float*)d_in[4];
    const float* b1 = (const float*)d_in[5];
    const float* W2 = (const float*)d_in[6];
    const float* b2 = (const float*)d_in[7];
    float* out = (float*)d_out;

    const int* row = ei;             // edge_index[0]
    const int* col = ei + N_EDGES;   // edge_index[1]

    // workspace layout (all segments 16B-aligned)
    float* dinv    = (float*)d_ws;                 // NPAD
    int*   counts  = (int*)(dinv + NPAD);          // NPAD
    int*   offsets = counts + NPAD;                // NPAD (N+1 used)
    int*   partials= offsets + NPAD;               // 256
    int*   rank_buf= partials + 256;               // N_EDGES
    int*   csr     = rank_buf + N_EDGES;           // N_EDGES
    ushort* hw     = (ushort*)(csr + N_EDGES);     // N*D bf16 (12.8 MB)

    int nb_e4 = (N_EDGES / 4 + 255) / 256;         // 782

    hipMemsetAsync(counts, 0, NPAD * sizeof(int), stream);
    k_count<<<nb_e4, 256, 0, stream>>>(col, counts, rank_buf);
    k_scan_local<<<NBLK, 256, 0, stream>>>(counts, offsets, partials);
    k_scan_add<<<NBLK, 256, 0, stream>>>(offsets, partials, counts, dinv);
    k_fill<<<nb_e4, 256, 0, stream>>>(row, col, offsets, rank_buf, csr);

    int nb_agg = N_NODES / 4;   // 4 nodes (waves) per block

    const float* Ws_[3] = {W0, W1, W2};
    const float* bs_[3] = {b0, b1, b2};
    for (int l = 0; l < 3; ++l) {
        const float* h;
        int stride;
        if (l == 0) { h = x; stride = D; }
        else        { h = out + (size_t)(l - 1) * D; stride = 3 * D; }
        k_gemm<<<GEMM_BLOCKS, 256, 0, stream>>>(h, stride, Ws_[l], dinv, hw);
        k_agg<<<nb_agg, 256, 0, stream>>>(hw, dinv, offsets, csr, bs_[l], out, l);
    }
}

// Round 6
// 309.016 us; speedup vs baseline: 2.4656x; 1.1509x over previous
//
#include <hip/hip_runtime.h>
#include <math.h>

#define N_NODES 50000
#define N_EDGES 800000
#define D 128
#define NPAD 50048   // N rounded up, keeps segments 16B-aligned
#define NBLK 196     // ceil(N_NODES/256)

typedef unsigned int uint32;
typedef __attribute__((ext_vector_type(8))) short short8;   // 8 bf16 (4 VGPRs)
typedef __attribute__((ext_vector_type(4))) float f32x4;    // MFMA C/D

__device__ __forceinline__ ushort f2bf(float f) {
    uint32 u = __float_as_uint(f);
    u = (u + 0x7fff + ((u >> 16) & 1)) >> 16;   // round-to-nearest-even
    return (ushort)u;
}
__device__ __forceinline__ float bf2f(ushort u) {
    return __uint_as_float(((uint32)u) << 16);
}

// ---------------------------------------------------------------------------
// CSR build: count (+record rank) -> local scan -> fused base add -> fill
// ---------------------------------------------------------------------------

__global__ __launch_bounds__(256) void k_count(const int* __restrict__ col,
                                               int* __restrict__ counts,
                                               int* __restrict__ rank_buf) {
    int i4 = (blockIdx.x * 256 + threadIdx.x) * 4;
    if (i4 < N_EDGES) {   // N_EDGES % 4 == 0
        int4 c = *(const int4*)(col + i4);
        int4 r;
        r.x = atomicAdd(&counts[c.x], 1);
        r.y = atomicAdd(&counts[c.y], 1);
        r.z = atomicAdd(&counts[c.z], 1);
        r.w = atomicAdd(&counts[c.w], 1);
        *(int4*)(rank_buf + i4) = r;
    }
}

__global__ __launch_bounds__(256) void k_scan_local(const int* __restrict__ counts,
                                                    int* __restrict__ offsets,
                                                    int* __restrict__ partials) {
    __shared__ int wsum[4];
    int tid = threadIdx.x;
    int i = blockIdx.x * 256 + tid;
    int v = (i < N_NODES) ? counts[i] : 0;
    int lane = tid & 63, wv = tid >> 6;
    int x = v;
    #pragma unroll
    for (int off = 1; off < 64; off <<= 1) {
        int y = __shfl_up(x, off);
        if (lane >= off) x += y;
    }
    if (lane == 63) wsum[wv] = x;
    __syncthreads();
    int b0 = wsum[0], b1 = wsum[1], b2 = wsum[2], b3 = wsum[3];
    int base = (wv > 0 ? b0 : 0) + (wv > 1 ? b1 : 0) + (wv > 2 ? b2 : 0);
    if (i < N_NODES) offsets[i] = base + x - v;
    if (tid == 255) partials[blockIdx.x] = b0 + b1 + b2 + b3;
}

__global__ __launch_bounds__(256) void k_scan_add(int* __restrict__ offsets,
                                                  const int* __restrict__ partials,
                                                  const int* __restrict__ counts,
                                                  float* __restrict__ dinv) {
    __shared__ int wsum[4];
    int tid = threadIdx.x;
    int p = (tid < (int)blockIdx.x && tid < NBLK) ? partials[tid] : 0;
    int lane = tid & 63, wv = tid >> 6;
    #pragma unroll
    for (int off = 32; off; off >>= 1) p += __shfl_down(p, off);
    if (lane == 0) wsum[wv] = p;
    __syncthreads();
    int base = wsum[0] + wsum[1] + wsum[2] + wsum[3];
    int i = blockIdx.x * 256 + tid;
    if (i < N_NODES) {
        offsets[i] += base;
        dinv[i] = rsqrtf((float)counts[i] + 1.0f);  // +1 self-loop
    }
    if (i == 0) offsets[N_NODES] = N_EDGES;
}

__global__ __launch_bounds__(256) void k_fill(const int* __restrict__ row,
                                              const int* __restrict__ col,
                                              const int* __restrict__ offsets,
                                              const int* __restrict__ rank_buf,
                                              int* __restrict__ csr_rows) {
    int i4 = (blockIdx.x * 256 + threadIdx.x) * 4;
    if (i4 < N_EDGES) {
        int4 c = *(const int4*)(col + i4);
        int4 r = *(const int4*)(rank_buf + i4);
        int4 rw = *(const int4*)(row + i4);
        csr_rows[offsets[c.x] + r.x] = rw.x;
        csr_rows[offsets[c.y] + r.y] = rw.y;
        csr_rows[offsets[c.z] + r.z] = rw.z;
        csr_rows[offsets[c.w] + r.w] = rw.w;
    }
}

// ---------------------------------------------------------------------------
// MFMA GEMM: hw_bf16[N,D] = bf16( dinv[.] * (h @ W) ), h from fp32 (layer 0)
// or packed bf16 hnext (layers 1,2). 64-row tiles, 4 waves x 16 rows.
// Wt[n][k] (transposed, bf16) + As (bf16), both stride-136 padded.
// mfma_f32_16x16x32_bf16: A[m=lane&15][k=(lane>>4)*8+j]; B[k=(lane>>4)*8+j][n=lane&15];
// D col=lane&15, row=(lane>>4)*4+reg  (guide §3, m89/m120-verified).
// ---------------------------------------------------------------------------
#define BM 64
#define LDA 136                         // padded ushort stride (272B, 16B-aligned)
#define NTILES ((N_NODES + BM - 1) / BM)  // 782
#define GEMM_BLOCKS 512

__global__ __launch_bounds__(256) void k_gemm(const float* __restrict__ hf,
                                              const ushort* __restrict__ hb,
                                              const float* __restrict__ W,
                                              const float* __restrict__ dinv,
                                              ushort* __restrict__ hw) {
    __shared__ __align__(16) ushort As[BM * LDA];   // 17.0 KB
    __shared__ __align__(16) ushort Wt[D * LDA];    // 34.8 KB
    int tid = threadIdx.x;
    int lane = tid & 63;
    int w = tid >> 6;
    int quad = lane >> 4;
    int m16 = lane & 15;

    // stage Wt[n][k] = bf16(W[k][n]); coalesced fp32 reads
    #pragma unroll 4
    for (int i = 0; i < 64; ++i) {
        int flat = tid + 256 * i;          // 16384 elems
        int k = flat >> 7, n = flat & 127;
        Wt[n * LDA + k] = f2bf(W[flat]);
    }

    for (int t = blockIdx.x; t < NTILES; t += GEMM_BLOCKS) {
        int row0 = t * BM;
        __syncthreads();   // previous tile fully consumed (also covers Wt once)

        // stage A tile: 64 rows x 128 cols bf16; thread owns 32 consecutive elems
        {
            int base = tid * 32;
            int r = base >> 7, c = base & 127;
            int row = row0 + r;
            ushort* dst = As + r * LDA + c;
            if (hf) {
                if (row < N_NODES) {
                    const float4* src = (const float4*)(hf + (size_t)row * D + c);
                    #pragma unroll
                    for (int j = 0; j < 4; ++j) {
                        float4 v0 = src[2 * j], v1 = src[2 * j + 1];
                        ushort4 u0, u1;
                        u0.x = f2bf(v0.x); u0.y = f2bf(v0.y); u0.z = f2bf(v0.z); u0.w = f2bf(v0.w);
                        u1.x = f2bf(v1.x); u1.y = f2bf(v1.y); u1.z = f2bf(v1.z); u1.w = f2bf(v1.w);
                        *(ushort4*)(dst + 8 * j) = u0;
                        *(ushort4*)(dst + 8 * j + 4) = u1;
                    }
                } else {
                    short8 z = {};
                    #pragma unroll
                    for (int j = 0; j < 4; ++j) *(short8*)(dst + 8 * j) = z;
                }
            } else {
                if (row < N_NODES) {
                    const short8* src = (const short8*)(hb + (size_t)row * D + c);
                    #pragma unroll
                    for (int j = 0; j < 4; ++j) *(short8*)(dst + 8 * j) = src[j];
                } else {
                    short8 z = {};
                    #pragma unroll
                    for (int j = 0; j < 4; ++j) *(short8*)(dst + 8 * j) = z;
                }
            }
        }
        __syncthreads();

        // compute: wave w -> rows 16w..16w+15, all 128 cols (8 col-tiles)
        f32x4 acc[8];
        #pragma unroll
        for (int ct = 0; ct < 8; ++ct) acc[ct] = (f32x4){0.f, 0.f, 0.f, 0.f};
        #pragma unroll
        for (int ks = 0; ks < 4; ++ks) {
            short8 a = *(const short8*)(As + (w * 16 + m16) * LDA + ks * 32 + quad * 8);
            #pragma unroll
            for (int ct = 0; ct < 8; ++ct) {
                short8 b = *(const short8*)(Wt + (ct * 16 + m16) * LDA + ks * 32 + quad * 8);
                acc[ct] = __builtin_amdgcn_mfma_f32_16x16x32_bf16(a, b, acc[ct], 0, 0, 0);
            }
        }

        // epilogue: scale by dinv, bf16 via own As rows (wave-exclusive), store
        float dv[4];
        #pragma unroll
        for (int r = 0; r < 4; ++r) {
            int row = row0 + w * 16 + quad * 4 + r;
            dv[r] = (row < N_NODES) ? dinv[row] : 0.f;
        }
        #pragma unroll
        for (int ct = 0; ct < 8; ++ct) {
            #pragma unroll
            for (int r = 0; r < 4; ++r)
                As[(w * 16 + quad * 4 + r) * LDA + ct * 16 + m16] = f2bf(acc[ct][r] * dv[r]);
        }
        // store 16 rows x 128 cols: 256 chunks of 8 elems (16B), 4 iters x 64 lanes
        #pragma unroll
        for (int i = 0; i < 4; ++i) {
            int chunk = i * 64 + lane;
            int r = chunk >> 4, c8 = chunk & 15;
            int row = row0 + w * 16 + r;
            if (row < N_NODES) {
                short8 v = *(const short8*)(As + (w * 16 + r) * LDA + c8 * 8);
                *(short8*)(hw + (size_t)row * D + c8 * 8) = v;
            }
        }
    }
}

// ---------------------------------------------------------------------------
// Aggregate (bf16 rows): one WAVE per node; halves split edge parity;
// writes fp32 out + (layers 0,1) packed bf16 hnext for the next GEMM.
// ---------------------------------------------------------------------------
__global__ __launch_bounds__(256) void k_agg(const ushort* __restrict__ hw,
                                             const float* __restrict__ dinv,
                                             const int* __restrict__ offsets,
                                             const int* __restrict__ csr_rows,
                                             const float* __restrict__ bias,
                                             float* __restrict__ out, int layer,
                                             ushort* __restrict__ hnext, int write_next) {
    int node = blockIdx.x * 4 + (threadIdx.x >> 6);
    int lane = threadIdx.x & 63;
    int h = lane >> 5;
    int ls = lane & 31;

    float4 acc = make_float4(0.f, 0.f, 0.f, 0.f);
    int s = offsets[node], e = offsets[node + 1];
    int j = s + h;
    for (; j + 6 < e; j += 8) {
        int r0 = csr_rows[j];
        int r1 = csr_rows[j + 2];
        int r2 = csr_rows[j + 4];
        int r3 = csr_rows[j + 6];
        ushort4 v0 = *((const ushort4*)(hw + (size_t)r0 * D) + ls);
        ushort4 v1 = *((const ushort4*)(hw + (size_t)r1 * D) + ls);
        ushort4 v2 = *((const ushort4*)(hw + (size_t)r2 * D) + ls);
        ushort4 v3 = *((const ushort4*)(hw + (size_t)r3 * D) + ls);
        acc.x += bf2f(v0.x) + bf2f(v1.x) + bf2f(v2.x) + bf2f(v3.x);
        acc.y += bf2f(v0.y) + bf2f(v1.y) + bf2f(v2.y) + bf2f(v3.y);
        acc.z += bf2f(v0.z) + bf2f(v1.z) + bf2f(v2.z) + bf2f(v3.z);
        acc.w += bf2f(v0.w) + bf2f(v1.w) + bf2f(v2.w) + bf2f(v3.w);
    }
    for (; j < e; j += 2) {
        int r = csr_rows[j];
        ushort4 v = *((const ushort4*)(hw + (size_t)r * D) + ls);
        acc.x += bf2f(v.x); acc.y += bf2f(v.y);
        acc.z += bf2f(v.z); acc.w += bf2f(v.w);
    }
    acc.x += __shfl_xor(acc.x, 32);
    acc.y += __shfl_xor(acc.y, 32);
    acc.z += __shfl_xor(acc.z, 32);
    acc.w += __shfl_xor(acc.w, 32);

    if (h == 0) {
        float di = dinv[node];
        ushort4 sv = *((const ushort4*)(hw + (size_t)node * D) + ls);
        float4 b = *((const float4*)bias + ls);
        float4 o;
        o.x = tanhf(di * (acc.x + bf2f(sv.x)) + b.x);
        o.y = tanhf(di * (acc.y + bf2f(sv.y)) + b.y);
        o.z = tanhf(di * (acc.z + bf2f(sv.z)) + b.z);
        o.w = tanhf(di * (acc.w + bf2f(sv.w)) + b.w);
        *((float4*)(out + ((size_t)node * 3 + layer) * D) + ls) = o;
        if (write_next) {
            ushort4 nv;
            nv.x = f2bf(o.x); nv.y = f2bf(o.y); nv.z = f2bf(o.z); nv.w = f2bf(o.w);
            *((ushort4*)(hnext + (size_t)node * D) + ls) = nv;
        }
    }
}

// ---------------------------------------------------------------------------

extern "C" void kernel_launch(void* const* d_in, const int* in_sizes, int n_in,
                              void* d_out, int out_size, void* d_ws, size_t ws_size,
                              hipStream_t stream) {
    const float* x  = (const float*)d_in[0];
    const int*   ei = (const int*)d_in[1];
    const float* W0 = (const float*)d_in[2];
    const float* b0 = (const float*)d_in[3];
    const float* W1 = (const float*)d_in[4];
    const float* b1 = (const float*)d_in[5];
    const float* W2 = (const float*)d_in[6];
    const float* b2 = (const float*)d_in[7];
    float* out = (float*)d_out;

    const int* row = ei;             // edge_index[0]
    const int* col = ei + N_EDGES;   // edge_index[1]

    // workspace layout (all segments 16B-aligned)
    float* dinv    = (float*)d_ws;                 // NPAD
    int*   counts  = (int*)(dinv + NPAD);          // NPAD
    int*   offsets = counts + NPAD;                // NPAD (N+1 used)
    int*   partials= offsets + NPAD;               // 256
    int*   rank_buf= partials + 256;               // N_EDGES
    int*   csr     = rank_buf + N_EDGES;           // N_EDGES
    ushort* hw     = (ushort*)(csr + N_EDGES);     // NPAD*D bf16
    ushort* hnext  = hw + (size_t)NPAD * D;        // NPAD*D bf16

    int nb_e4 = (N_EDGES / 4 + 255) / 256;         // 782

    hipMemsetAsync(counts, 0, NPAD * sizeof(int), stream);
    k_count<<<nb_e4, 256, 0, stream>>>(col, counts, rank_buf);
    k_scan_local<<<NBLK, 256, 0, stream>>>(counts, offsets, partials);
    k_scan_add<<<NBLK, 256, 0, stream>>>(offsets, partials, counts, dinv);
    k_fill<<<nb_e4, 256, 0, stream>>>(row, col, offsets, rank_buf, csr);

    int nb_agg = N_NODES / 4;   // 4 nodes (waves) per block

    const float* Ws_[3] = {W0, W1, W2};
    const float* bs_[3] = {b0, b1, b2};
    for (int l = 0; l < 3; ++l) {
        if (l == 0) k_gemm<<<GEMM_BLOCKS, 256, 0, stream>>>(x, (const ushort*)nullptr, Ws_[l], dinv, hw);
        else        k_gemm<<<GEMM_BLOCKS, 256, 0, stream>>>((const float*)nullptr, hnext, Ws_[l], dinv, hw);
        k_agg<<<nb_agg, 256, 0, stream>>>(hw, dinv, offsets, csr, bs_[l], out, l,
                                          hnext, l < 2 ? 1 : 0);
    }
}